// Round 3
// baseline (839.257 us; speedup 1.0000x reference)
//
#include <hip/hip_runtime.h>
#include <hip/hip_bf16.h>

typedef __hip_bfloat16 bf16;

__device__ __forceinline__ float cvt(float v){ return v; }
__device__ __forceinline__ float cvt(bf16 v){ return __bfloat162float(v); }

// ---- workspace layout (floats) ----
constexpr size_t O_COMP = 0;                               // (8,128,64,64)
constexpr size_t O_T    = O_COMP + 8UL*128*4096;           // (8,64,64,64)
constexpr size_t O_KW   = O_T    + 8UL*64*4096;            // (8,4096,36) softmaxed
constexpr size_t O_ENH  = O_KW   + 8UL*4096*36;            // (8,256,64,64)
constexpr size_t O_POOL = O_ENH  + 8UL*256*4096;           // (8,256)
constexpr size_t O_GATE = O_POOL + 2048;                   // (8,256)
constexpr size_t O_WKC  = O_GATE + 2048;                   // 128*256
constexpr size_t O_BKC  = O_WKC  + 32768;                  // 128
constexpr size_t O_WKP1 = O_BKC  + 128;                    // 64*128*9
constexpr size_t O_ALPHA= O_WKP1 + 73728;                  // 64 (BN scale)
constexpr size_t O_BETA = O_ALPHA+ 64;                     // 64 (BN shift incl conv bias)
constexpr size_t O_WKP2 = O_BETA + 64;                     // 36*64
constexpr size_t O_BKP2 = O_WKP2 + 2304;                   // 36 (padded 64)
constexpr size_t O_WDEF = O_BKP2 + 64;                     // 256*64*9
constexpr size_t O_WG1  = O_WDEF + 147456;                 // 64*256
constexpr size_t O_BG1  = O_WG1  + 16384;                  // 64
constexpr size_t O_WG2  = O_BG1  + 64;                     // 256*64
constexpr size_t O_BG2  = O_WG2  + 16384;                  // 256
constexpr size_t O_FLAG = O_BG2  + 256;                    // 1: 1.0=fp32 inputs, 0.0=bf16

// ---- kdet: input dtype from Wkc bit patterns (proven: fp32 -> ~64 hits) ----
__global__ __launch_bounds__(256) void kdet(const unsigned* __restrict__ w, float* flag)
{
    int hits = 0;
    for (int i = threadIdx.x; i < 16384; i += 256){
        unsigned v = w[i];
        hits += (((v >> 7) & 0xFFu) == 0xFFu) ? 1 : 0;
    }
    __shared__ int sh[256];
    sh[threadIdx.x] = hits;
    __syncthreads();
    for (int o = 128; o > 0; o >>= 1){
        if (threadIdx.x < o) sh[threadIdx.x] += sh[threadIdx.x + o];
        __syncthreads();
    }
    if (threadIdx.x == 0) flag[0] = (sh[0] > 0) ? 1.0f : 0.0f;
}

// ---- k0: convert all weights ->fp32, fold BN into (alpha,beta) ----
template<typename T>
__device__ __forceinline__ void k0_body(
    const T* Wkc, const T* bkc, const T* Wkp1, const T* bkp1,
    const T* g1, const T* be1, const T* m1, const T* v1,
    const T* Wkp2, const T* bkp2, const T* Wdef,
    const T* Wg1, const T* bg1, const T* Wg2, const T* bg2,
    float* ws)
{
    int i = blockIdx.x*256 + threadIdx.x;
    if (i < 32768){ ws[O_WKC+i] = cvt(Wkc[i]); return; }  i -= 32768;
    if (i < 128)  { ws[O_BKC+i] = cvt(bkc[i]); return; }  i -= 128;
    if (i < 73728){ ws[O_WKP1+i]= cvt(Wkp1[i]); return; } i -= 73728;
    if (i < 64){
        float a = cvt(g1[i]) / sqrtf(cvt(v1[i]) + 1e-5f);
        ws[O_ALPHA+i] = a;
        ws[O_BETA+i]  = (cvt(bkp1[i]) - cvt(m1[i]))*a + cvt(be1[i]);
        return;
    } i -= 64;
    if (i < 2304) { ws[O_WKP2+i] = cvt(Wkp2[i]); return; } i -= 2304;
    if (i < 36)   { ws[O_BKP2+i] = cvt(bkp2[i]); return; } i -= 36;
    if (i < 147456){ ws[O_WDEF+i]= cvt(Wdef[i]); return; } i -= 147456;
    if (i < 16384){ ws[O_WG1+i]  = cvt(Wg1[i]); return; }  i -= 16384;
    if (i < 64)   { ws[O_BG1+i]  = cvt(bg1[i]); return; }  i -= 64;
    if (i < 16384){ ws[O_WG2+i]  = cvt(Wg2[i]); return; }  i -= 16384;
    if (i < 256)  { ws[O_BG2+i]  = cvt(bg2[i]); return; }
}

__global__ __launch_bounds__(256) void k0_prep(
    const void* Wkc, const void* bkc, const void* Wkp1, const void* bkp1,
    const void* g1, const void* be1, const void* m1, const void* v1,
    const void* Wkp2, const void* bkp2, const void* Wdef,
    const void* Wg1, const void* bg1, const void* Wg2, const void* bg2,
    float* ws)
{
    if (ws[O_FLAG] > 0.5f)
        k0_body<float>((const float*)Wkc,(const float*)bkc,(const float*)Wkp1,(const float*)bkp1,
                       (const float*)g1,(const float*)be1,(const float*)m1,(const float*)v1,
                       (const float*)Wkp2,(const float*)bkp2,(const float*)Wdef,
                       (const float*)Wg1,(const float*)bg1,(const float*)Wg2,(const float*)bg2, ws);
    else
        k0_body<bf16>((const bf16*)Wkc,(const bf16*)bkc,(const bf16*)Wkp1,(const bf16*)bkp1,
                      (const bf16*)g1,(const bf16*)be1,(const bf16*)m1,(const bf16*)v1,
                      (const bf16*)Wkp2,(const bf16*)bkp2,(const bf16*)Wdef,
                      (const bf16*)Wg1,(const bf16*)bg1,(const bf16*)Wg2,(const bf16*)bg2, ws);
}

// ---- k1: 1x1 conv x(256) -> comp(128), bias ----
template<typename T>
__device__ __forceinline__ void k1_body(
    const T* __restrict__ x, const float* __restrict__ W,
    const float* __restrict__ bias, float* __restrict__ comp)
{
    const int pos = blockIdx.x*256 + threadIdx.x;
    const int co0 = blockIdx.y*4;
    const int b   = blockIdx.z;
    const T* xp = x + (size_t)b*256*4096 + pos;
    const float* wp = W + (size_t)co0*256;
    float a0=bias[co0], a1=bias[co0+1], a2=bias[co0+2], a3=bias[co0+3];
    #pragma unroll 4
    for (int ci=0; ci<256; ++ci){
        float xv = cvt(xp[(size_t)ci*4096]);
        a0 += xv*wp[ci]; a1 += xv*wp[256+ci]; a2 += xv*wp[512+ci]; a3 += xv*wp[768+ci];
    }
    float* op = comp + ((size_t)b*128 + co0)*4096 + pos;
    op[0]=a0; op[4096]=a1; op[8192]=a2; op[12288]=a3;
}

__global__ __launch_bounds__(256) void k1_conv1x1(
    const void* x, const float* W, const float* bias, float* comp, const float* flag)
{
    if (*flag > 0.5f) k1_body<float>((const float*)x, W, bias, comp);
    else              k1_body<bf16>((const bf16*)x, W, bias, comp);
}

// ---- k2: 3x3 conv comp(128)->64, BN+SiLU ----
__global__ __launch_bounds__(256) void k2_conv3x3(
    const float* __restrict__ comp, const float* __restrict__ W,
    const float* __restrict__ alpha, const float* __restrict__ beta,
    float* __restrict__ t)
{
    const int xx = threadIdx.x;                 // 0..63
    const int y  = blockIdx.x*4 + threadIdx.y;  // 0..63
    const int co0= blockIdx.y*4;
    const int b  = blockIdx.z;
    const bool vy0=y>0, vy2=y<63, vx0=xx>0, vx2=xx<63;
    const float* cb = comp + (size_t)b*128*4096;
    float acc[4] = {0.f,0.f,0.f,0.f};
    for (int ci=0; ci<128; ++ci){
        const float* p = cb + (size_t)ci*4096;
        float v[9];
        v[0] = (vy0&&vx0)? p[(y-1)*64+xx-1] : 0.f;
        v[1] = (vy0)     ? p[(y-1)*64+xx  ] : 0.f;
        v[2] = (vy0&&vx2)? p[(y-1)*64+xx+1] : 0.f;
        v[3] = (vx0)     ? p[ y   *64+xx-1] : 0.f;
        v[4] =             p[ y   *64+xx  ];
        v[5] = (vx2)     ? p[ y   *64+xx+1] : 0.f;
        v[6] = (vy2&&vx0)? p[(y+1)*64+xx-1] : 0.f;
        v[7] = (vy2)     ? p[(y+1)*64+xx  ] : 0.f;
        v[8] = (vy2&&vx2)? p[(y+1)*64+xx+1] : 0.f;
        #pragma unroll
        for (int j=0;j<4;j++){
            const float* w = W + ((size_t)(co0+j)*128 + ci)*9;
            #pragma unroll
            for (int k=0;k<9;k++) acc[j] += v[k]*w[k];
        }
    }
    #pragma unroll
    for (int j=0;j<4;j++){
        float z = acc[j]*alpha[co0+j] + beta[co0+j];
        float s = z/(1.f+expf(-z));
        t[((size_t)b*64 + co0+j)*4096 + y*64 + xx] = s;
    }
}

// ---- k3: 1x1 conv t(64)->36 + softmax over groups of 9 ----
__global__ __launch_bounds__(256) void k3_kpred(
    const float* __restrict__ t, const float* __restrict__ W,
    const float* __restrict__ bias, float* __restrict__ kw)
{
    __shared__ float wl[2304];
    __shared__ float bl[36];
    for (int i=threadIdx.x;i<2304;i+=256) wl[i]=W[i];
    if (threadIdx.x<36) bl[threadIdx.x]=bias[threadIdx.x];
    __syncthreads();
    const int gid = blockIdx.x*256 + threadIdx.x;    // b*4096+pos
    const int b = gid>>12, pos = gid&4095;
    const float* tp = t + (size_t)b*64*4096 + pos;
    float acc[36];
    #pragma unroll
    for (int o=0;o<36;o++) acc[o]=bl[o];
    for (int ci=0; ci<64; ++ci){
        float tv = tp[(size_t)ci*4096];
        #pragma unroll
        for (int o=0;o<36;o++) acc[o] += tv*wl[o*64+ci];
    }
    float* op = kw + (size_t)gid*36;
    #pragma unroll
    for (int s=0;s<4;s++){
        float mx = acc[s*9];
        #pragma unroll
        for (int k=1;k<9;k++) mx = fmaxf(mx, acc[s*9+k]);
        float e[9]; float sum=0.f;
        #pragma unroll
        for (int k=0;k<9;k++){ e[k]=expf(acc[s*9+k]-mx); sum+=e[k]; }
        float inv = 1.f/sum;
        #pragma unroll
        for (int k=0;k<9;k++) op[s*9+k] = e[k]*inv;
    }
}

// ---- k4: grouped 3x3 conv x(256,g=4)->enh(256), no bias ----
template<typename T>
__device__ __forceinline__ void k4_body(
    const T* __restrict__ x, const float* __restrict__ W, float* __restrict__ enh)
{
    const int xx = threadIdx.x;
    const int y  = blockIdx.x*4 + threadIdx.y;
    const int co0= blockIdx.y*4;
    const int b  = blockIdx.z;
    const int g  = co0>>6;
    const bool vy0=y>0, vy2=y<63, vx0=xx>0, vx2=xx<63;
    const T* xb = x + ((size_t)b*256 + g*64)*4096;
    float acc[4] = {0.f,0.f,0.f,0.f};
    for (int ci=0; ci<64; ++ci){
        const T* p = xb + (size_t)ci*4096;
        float v[9];
        v[0] = (vy0&&vx0)? cvt(p[(y-1)*64+xx-1]) : 0.f;
        v[1] = (vy0)     ? cvt(p[(y-1)*64+xx  ]) : 0.f;
        v[2] = (vy0&&vx2)? cvt(p[(y-1)*64+xx+1]) : 0.f;
        v[3] = (vx0)     ? cvt(p[ y   *64+xx-1]) : 0.f;
        v[4] =             cvt(p[ y   *64+xx  ]);
        v[5] = (vx2)     ? cvt(p[ y   *64+xx+1]) : 0.f;
        v[6] = (vy2&&vx0)? cvt(p[(y+1)*64+xx-1]) : 0.f;
        v[7] = (vy2)     ? cvt(p[(y+1)*64+xx  ]) : 0.f;
        v[8] = (vy2&&vx2)? cvt(p[(y+1)*64+xx+1]) : 0.f;
        #pragma unroll
        for (int j=0;j<4;j++){
            const float* w = W + ((size_t)(co0+j)*64 + ci)*9;
            #pragma unroll
            for (int k=0;k<9;k++) acc[j] += v[k]*w[k];
        }
    }
    #pragma unroll
    for (int j=0;j<4;j++)
        enh[((size_t)b*256 + co0+j)*4096 + y*64 + xx] = acc[j];
}

__global__ __launch_bounds__(256) void k4_gconv(
    const void* x, const float* W, float* enh, const float* flag)
{
    if (*flag > 0.5f) k4_body<float>((const float*)x, W, enh);
    else              k4_body<bf16>((const bf16*)x, W, enh);
}

// ---- k5: reassembly (einsum) + bilinear upsample add -> out (fp32) ----
template<typename T>
__device__ __forceinline__ void k5_body(
    const T* __restrict__ x, const float* __restrict__ kw,
    const float* __restrict__ enh, float* __restrict__ out)
{
    const int hi = blockIdx.x & 63;
    const int b  = blockIdx.x >> 6;
    const int c0 = blockIdx.y * 64;
    __shared__ float kwl[64*37];   // pad 36->37: stride-36 would be 8-way bank conflict
    for (int i=threadIdx.x;i<2304;i+=256){
        int wi = i/36, r = i - wi*36;
        kwl[wi*37+r] = kw[((size_t)(b*4096 + hi*64 + wi))*36 + r];
    }
    __syncthreads();
    const int wi = threadIdx.x & 63;
    const int cl = threadIdx.x >> 6;
    float kreg[36];
    #pragma unroll
    for (int r=0;r<36;r++) kreg[r] = kwl[wi*37+r];

    const bool vx0 = wi>0, vx2 = wi<63;
    const bool vy0 = hi>0, vy2 = hi<63;
    const int rm = vy0? hi-1 : 0;
    const int rp = vy2? hi+1 : 63;
    const int par = wi&1;
    const int mA = wi>>1, mB = 32+mA;
    float wc0, wc1; int a0,a1,b0c,b1c;
    if (par==0){ wc0=0.25f; wc1=0.75f; a0=(mA>0)?mA-1:0; a1=mA;   b0c=mB-1; b1c=mB; }
    else       { wc0=0.75f; wc1=0.25f; a0=mA;            a1=mA+1; b0c=mB;   b1c=(mB<63)?mB+1:63; }
    const int y0 = hi*2;

    for (int c = c0+cl; c < c0+64; c += 4){
        const T* xc = x + ((size_t)(b*256)+c)*4096;
        float v[9];
        v[0] = (vy0&&vx0)? cvt(xc[(hi-1)*64+wi-1]) : 0.f;
        v[1] = (vy0)     ? cvt(xc[(hi-1)*64+wi  ]) : 0.f;
        v[2] = (vy0&&vx2)? cvt(xc[(hi-1)*64+wi+1]) : 0.f;
        v[3] = (vx0)     ? cvt(xc[ hi   *64+wi-1]) : 0.f;
        v[4] =             cvt(xc[ hi   *64+wi  ]);
        v[5] = (vx2)     ? cvt(xc[ hi   *64+wi+1]) : 0.f;
        v[6] = (vy2&&vx0)? cvt(xc[(hi+1)*64+wi-1]) : 0.f;
        v[7] = (vy2)     ? cvt(xc[(hi+1)*64+wi  ]) : 0.f;
        v[8] = (vy2&&vx2)? cvt(xc[(hi+1)*64+wi+1]) : 0.f;
        float ko[4];
        #pragma unroll
        for (int s=0;s<4;s++){
            float a = 0.f;
            #pragma unroll
            for (int k=0;k<9;k++) a += v[k]*kreg[s*9+k];
            ko[s]=a;
        }
        const float* ec = enh + ((size_t)(b*256)+c)*4096;
        const float* er0 = ec + rm*64;
        const float* er1 = ec + hi*64;
        const float* er2 = ec + rp*64;
        float uA0 = wc0*er0[a0]+wc1*er0[a1];
        float uB0 = wc0*er0[b0c]+wc1*er0[b1c];
        float uA1 = wc0*er1[a0]+wc1*er1[a1];
        float uB1 = wc0*er1[b0c]+wc1*er1[b1c];
        float uA2 = wc0*er2[a0]+wc1*er2[a1];
        float uB2 = wc0*er2[b0c]+wc1*er2[b1c];
        float up00 = 0.25f*uA0 + 0.75f*uA1;
        float up01 = 0.25f*uB0 + 0.75f*uB1;
        float up10 = 0.75f*uA1 + 0.25f*uA2;
        float up11 = 0.75f*uB1 + 0.25f*uB2;
        float* o = out + (((size_t)(b*256)+c)*128 + y0)*128;
        o[wi]      = ko[0]+up00;
        o[64+wi]   = ko[1]+up01;
        o[128+wi]  = ko[2]+up10;
        o[192+wi]  = ko[3]+up11;
    }
}

__global__ __launch_bounds__(256) void k5_fuse(
    const void* x, const float* kw, const float* enh, float* out, const float* flag)
{
    if (*flag > 0.5f) k5_body<float>((const float*)x, kw, enh, out);
    else              k5_body<bf16>((const bf16*)x, kw, enh, out);
}

// ---- k6: spatial mean of fused per (b,c), fp32 float4 ----
__global__ __launch_bounds__(256) void k6_pool(
    const float* __restrict__ out, float* __restrict__ pooled)
{
    const int bc = blockIdx.x;
    const float4* p = (const float4*)(out + (size_t)bc*16384);
    float s = 0.f;
    #pragma unroll
    for (int k=0;k<16;k++){
        float4 v = p[k*256+threadIdx.x];
        s += v.x+v.y+v.z+v.w;
    }
    __shared__ float red[4];
    for (int off=32;off>0;off>>=1) s += __shfl_down(s, off, 64);
    if ((threadIdx.x&63)==0) red[threadIdx.x>>6]=s;
    __syncthreads();
    if (threadIdx.x==0) pooled[bc] = (red[0]+red[1]+red[2]+red[3]) * (1.f/16384.f);
}

// ---- k7: SE gate (per batch) ----
__global__ __launch_bounds__(256) void k7_gate(
    const float* __restrict__ pooled,
    const float* __restrict__ Wg1, const float* __restrict__ bg1,
    const float* __restrict__ Wg2, const float* __restrict__ bg2,
    float* __restrict__ gate)
{
    const int b = blockIdx.x;
    __shared__ float pl[256];
    __shared__ float hid[64];
    pl[threadIdx.x] = pooled[b*256+threadIdx.x];
    __syncthreads();
    if (threadIdx.x < 64){
        float a = bg1[threadIdx.x];
        const float* w = Wg1 + (size_t)threadIdx.x*256;
        for (int c=0;c<256;c++) a += w[c]*pl[c];
        hid[threadIdx.x] = a/(1.f+expf(-a));
    }
    __syncthreads();
    float a = bg2[threadIdx.x];
    const float* w = Wg2 + (size_t)threadIdx.x*64;
    for (int j=0;j<64;j++) a += w[j]*hid[j];
    gate[b*256+threadIdx.x] = 1.f/(1.f+expf(-a));
}

// ---- k8: out *= gate (broadcast over spatial), float4 ----
__global__ __launch_bounds__(256) void k8_scale(
    float* __restrict__ out, const float* __restrict__ gate)
{
    const size_t gid = (size_t)blockIdx.x*256 + threadIdx.x;  // 8.39M float4
    const float g = gate[gid>>12];                            // 4096 float4 per (b,c)
    float4* p = (float4*)out;
    float4 v = p[gid];
    v.x*=g; v.y*=g; v.z*=g; v.w*=g;
    p[gid] = v;
}

extern "C" void kernel_launch(void* const* d_in, const int* in_sizes, int n_in,
                              void* d_out, int out_size, void* d_ws, size_t ws_size,
                              hipStream_t stream)
{
    float* ws = (float*)d_ws;
    float* out = (float*)d_out;

    kdet<<<1, 256, 0, stream>>>((const unsigned*)d_in[1], ws + O_FLAG);
    k0_prep<<<1132, 256, 0, stream>>>(d_in[1],d_in[2],d_in[3],d_in[4],d_in[5],d_in[6],d_in[7],d_in[8],
                                      d_in[9],d_in[10],d_in[11],d_in[12],d_in[13],d_in[14],d_in[15], ws);
    k1_conv1x1<<<dim3(16,32,8), 256, 0, stream>>>(d_in[0], ws+O_WKC, ws+O_BKC, ws+O_COMP, ws+O_FLAG);
    k2_conv3x3<<<dim3(16,16,8), dim3(64,4), 0, stream>>>(ws+O_COMP, ws+O_WKP1, ws+O_ALPHA, ws+O_BETA, ws+O_T);
    k3_kpred<<<128, 256, 0, stream>>>(ws+O_T, ws+O_WKP2, ws+O_BKP2, ws+O_KW);
    k4_gconv<<<dim3(16,64,8), dim3(64,4), 0, stream>>>(d_in[0], ws+O_WDEF, ws+O_ENH, ws+O_FLAG);
    k5_fuse<<<dim3(512,4), 256, 0, stream>>>(d_in[0], ws+O_KW, ws+O_ENH, out, ws+O_FLAG);
    k6_pool<<<2048, 256, 0, stream>>>(out, ws+O_POOL);
    k7_gate<<<8, 256, 0, stream>>>(ws+O_POOL, ws+O_WG1, ws+O_BG1, ws+O_WG2, ws+O_BG2, ws+O_GATE);
    k8_scale<<<32768, 256, 0, stream>>>(out, ws+O_GATE);
}

// Round 4
// 442.999 us; speedup vs baseline: 1.8945x; 1.8945x over previous
//
#include <hip/hip_runtime.h>
#include <hip/hip_bf16.h>

typedef __hip_bfloat16 bf16;
typedef __attribute__((ext_vector_type(8))) short short8;
typedef __attribute__((ext_vector_type(4))) float floatx4;

__device__ __forceinline__ float cvt(float v){ return v; }
__device__ __forceinline__ float cvt(bf16 v){ return __bfloat162float(v); }
__device__ __forceinline__ unsigned short f2bu(float f){
    union { float f; unsigned u; } uf; uf.f = f;
    unsigned u = uf.u;
    return (unsigned short)((u + 0x7FFFu + ((u>>16)&1u)) >> 16);   // RNE
}
__device__ __forceinline__ float bu2f(unsigned short b){
    union { unsigned u; float f; } uf; uf.u = ((unsigned)b)<<16; return uf.f;
}
__device__ __forceinline__ floatx4 mfma16(short8 a, short8 b, floatx4 c){
    return __builtin_amdgcn_mfma_f32_16x16x32_bf16(a, b, c, 0, 0, 0);
}

// ---- workspace layout (float units) ----
constexpr size_t O_KW    = 0;                        // (8,4096,36) fp32 softmaxed
constexpr size_t O_ENH   = O_KW    + 1179648;        // (8,256,64,64) fp32 NCHW
constexpr size_t O_XBT   = O_ENH   + 8388608;        // bf16 NHWC [8][4096][256] -> 4194304 fl
constexpr size_t O_COMPB = O_XBT   + 4194304;        // bf16 NHWC [8][4096][128] -> 2097152 fl
constexpr size_t O_TB    = O_COMPB + 2097152;        // bf16 NHWC [8][4096][64]  -> 1048576 fl
constexpr size_t O_POOL  = O_TB    + 1048576;        // (8,256)
constexpr size_t O_GATE  = O_POOL  + 2048;           // (8,256)
constexpr size_t O_WKC   = O_GATE  + 2048;           // 128*256 fp32
constexpr size_t O_BKC   = O_WKC   + 32768;          // 128
constexpr size_t O_WKP1  = O_BKC   + 128;            // 64*128*9 fp32
constexpr size_t O_ALPHA = O_WKP1  + 73728;          // 64
constexpr size_t O_BETA  = O_ALPHA + 64;             // 64
constexpr size_t O_WKP2  = O_BETA  + 64;             // 36*64
constexpr size_t O_BKP2  = O_WKP2  + 2304;           // 36 (pad 64)
constexpr size_t O_WDEF  = O_BKP2  + 64;             // 256*64*9 fp32
constexpr size_t O_WG1   = O_WDEF  + 147456;         // 64*256
constexpr size_t O_BG1   = O_WG1   + 16384;          // 64
constexpr size_t O_WG2   = O_BG1   + 64;             // 256*64
constexpr size_t O_BG2   = O_WG2   + 16384;          // 256
constexpr size_t O_FLAG  = O_BG2   + 256;            // 1
constexpr size_t O_WKCB  = (O_FLAG + 1 + 3) & ~(size_t)3;   // bf16 [8kc][128][32] -> 16384 fl
constexpr size_t O_WKP1B = O_WKCB  + 16384;          // bf16 [4ch][9][64][32] -> 36864 fl
constexpr size_t O_WDEFB = O_WKP1B + 36864;          // bf16 [4g][2ch][9][64][32] -> 73728 fl

// ---- kdet: input dtype from Wkc bit patterns (proven: fp32 -> hits>0) ----
__global__ __launch_bounds__(256) void kdet(const unsigned* __restrict__ w, float* flag)
{
    int hits = 0;
    for (int i = threadIdx.x; i < 16384; i += 256){
        unsigned v = w[i];
        hits += (((v >> 7) & 0xFFu) == 0xFFu) ? 1 : 0;
    }
    __shared__ int sh[256];
    sh[threadIdx.x] = hits;
    __syncthreads();
    for (int o = 128; o > 0; o >>= 1){
        if (threadIdx.x < o) sh[threadIdx.x] += sh[threadIdx.x + o];
        __syncthreads();
    }
    if (threadIdx.x == 0) flag[0] = (sh[0] > 0) ? 1.0f : 0.0f;
}

// ---- k0: convert all weights ->fp32, fold BN ----
template<typename T>
__device__ __forceinline__ void k0_body(
    const T* Wkc, const T* bkc, const T* Wkp1, const T* bkp1,
    const T* g1, const T* be1, const T* m1, const T* v1,
    const T* Wkp2, const T* bkp2, const T* Wdef,
    const T* Wg1, const T* bg1, const T* Wg2, const T* bg2,
    float* ws)
{
    int i = blockIdx.x*256 + threadIdx.x;
    if (i < 32768){ ws[O_WKC+i] = cvt(Wkc[i]); return; }  i -= 32768;
    if (i < 128)  { ws[O_BKC+i] = cvt(bkc[i]); return; }  i -= 128;
    if (i < 73728){ ws[O_WKP1+i]= cvt(Wkp1[i]); return; } i -= 73728;
    if (i < 64){
        float a = cvt(g1[i]) / sqrtf(cvt(v1[i]) + 1e-5f);
        ws[O_ALPHA+i] = a;
        ws[O_BETA+i]  = (cvt(bkp1[i]) - cvt(m1[i]))*a + cvt(be1[i]);
        return;
    } i -= 64;
    if (i < 2304) { ws[O_WKP2+i] = cvt(Wkp2[i]); return; } i -= 2304;
    if (i < 36)   { ws[O_BKP2+i] = cvt(bkp2[i]); return; } i -= 36;
    if (i < 147456){ ws[O_WDEF+i]= cvt(Wdef[i]); return; } i -= 147456;
    if (i < 16384){ ws[O_WG1+i]  = cvt(Wg1[i]); return; }  i -= 16384;
    if (i < 64)   { ws[O_BG1+i]  = cvt(bg1[i]); return; }  i -= 64;
    if (i < 16384){ ws[O_WG2+i]  = cvt(Wg2[i]); return; }  i -= 16384;
    if (i < 256)  { ws[O_BG2+i]  = cvt(bg2[i]); return; }
}

__global__ __launch_bounds__(256) void k0_prep(
    const void* Wkc, const void* bkc, const void* Wkp1, const void* bkp1,
    const void* g1, const void* be1, const void* m1, const void* v1,
    const void* Wkp2, const void* bkp2, const void* Wdef,
    const void* Wg1, const void* bg1, const void* Wg2, const void* bg2,
    float* ws)
{
    if (ws[O_FLAG] > 0.5f)
        k0_body<float>((const float*)Wkc,(const float*)bkc,(const float*)Wkp1,(const float*)bkp1,
                       (const float*)g1,(const float*)be1,(const float*)m1,(const float*)v1,
                       (const float*)Wkp2,(const float*)bkp2,(const float*)Wdef,
                       (const float*)Wg1,(const float*)bg1,(const float*)Wg2,(const float*)bg2, ws);
    else
        k0_body<bf16>((const bf16*)Wkc,(const bf16*)bkc,(const bf16*)Wkp1,(const bf16*)bkp1,
                      (const bf16*)g1,(const bf16*)be1,(const bf16*)m1,(const bf16*)v1,
                      (const bf16*)Wkp2,(const bf16*)bkp2,(const bf16*)Wdef,
                      (const bf16*)Wg1,(const bf16*)bg1,(const bf16*)Wg2,(const bf16*)bg2, ws);
}

// ---- k0b: pack MFMA bf16 weight layouts from fp32 ws ----
__global__ __launch_bounds__(256) void k0b_pack(float* ws)
{
    unsigned short* wkcb  = (unsigned short*)(ws + O_WKCB);
    unsigned short* wkp1b = (unsigned short*)(ws + O_WKP1B);
    unsigned short* wdefb = (unsigned short*)(ws + O_WDEFB);
    int i = blockIdx.x*256 + threadIdx.x;
    if (i < 32768){                      // [kc8][cout128][cil32] <- Wkc[cout][256]
        int kc = i>>12, cout = (i>>5)&127, cil = i&31;
        wkcb[i] = f2bu(ws[O_WKC + (size_t)cout*256 + kc*32 + cil]);
        return;
    } i -= 32768;
    if (i < 73728){                      // [ch4][kp9][cout64][cil32] <- Wkp1[cout][128][9]
        int ch = i/18432, r = i - ch*18432;
        int kp = r>>11, cout = (r>>5)&63, cil = r&31;
        wkp1b[i] = f2bu(ws[O_WKP1 + ((size_t)cout*128 + ch*32 + cil)*9 + kp]);
        return;
    } i -= 73728;
    if (i < 147456){                     // [g4][ch2][kp9][cout64][cil32] <- Wdef[g*64+cout][64][9]
        int g = i/36864, r1 = i - g*36864;
        int ch = r1/18432, r2 = r1 - ch*18432;
        int kp = r2>>11, cout = (r2>>5)&63, cil = r2&31;
        wdefb[i] = f2bu(ws[O_WDEF + (((size_t)(g*64+cout))*64 + ch*32 + cil)*9 + kp]);
    }
}

// ---- xcvt: x (NCHW fp32/bf16) -> xbt (NHWC bf16) via LDS transpose ----
template<typename T>
__device__ __forceinline__ void xcvt_body(const T* __restrict__ x, unsigned short* __restrict__ xbt)
{
    __shared__ float lT[64*65];
    const int b = blockIdx.y;
    const int ci0 = (blockIdx.x & 3) * 64;
    const int pos0 = (blockIdx.x >> 2) * 64;
    const int lane = threadIdx.x & 63;
    const int wrow = threadIdx.x >> 6;
    for (int i = wrow; i < 64; i += 4)
        lT[i*65 + lane] = cvt(x[((size_t)(b*256 + ci0 + i))*4096 + pos0 + lane]);
    __syncthreads();
    for (int i = wrow; i < 64; i += 4)
        xbt[((size_t)(b*4096) + pos0 + i)*256 + ci0 + lane] = f2bu(lT[lane*65 + i]);
}

__global__ __launch_bounds__(256) void xcvt(const void* x, unsigned short* xbt, const float* flag)
{
    if (*flag > 0.5f) xcvt_body<float>((const float*)x, xbt);
    else              xcvt_body<bf16>((const bf16*)x, xbt);
}

// ---- k1: 1x1 conv as MFMA GEMM: [128 cout] x [256 ci] x [pos] -> compb NHWC bf16 ----
__global__ __launch_bounds__(256) void k1_mfma(
    const unsigned short* __restrict__ xbt, const unsigned short* __restrict__ wb,
    const float* __restrict__ bias, unsigned short* __restrict__ compb)
{
    __shared__ __align__(16) short lA[128*32];
    __shared__ __align__(16) short lB[128*32];
    const int b = blockIdx.y, pos0 = blockIdx.x*128;
    const int tid = threadIdx.x;
    const int wave = tid>>6, lane = tid&63, q = lane>>4, r16 = lane&15;
    const int mh = (wave&1)*64, nh = (wave>>1)*64;
    floatx4 zero = {0.f,0.f,0.f,0.f};
    floatx4 acc[4][4];
    #pragma unroll
    for (int m=0;m<4;m++){ acc[m][0]=zero; acc[m][1]=zero; acc[m][2]=zero; acc[m][3]=zero; }

    for (int kc=0;kc<8;kc++){
        __syncthreads();
        {   // stage A (weights): contiguous 4096 shorts
            const short8* s = (const short8*)(wb + kc*4096);
            short8* d = (short8*)lA;
            d[tid] = s[tid]; d[tid+256] = s[tid+256];
        }
        {   // stage B (x): [pos128][ci32]
            const int ci = tid&31, pr = tid>>5;
            #pragma unroll
            for (int p=pr; p<128; p+=8)
                lB[p*32+ci] = (short)xbt[((size_t)(b*4096)+pos0+p)*256 + kc*32 + ci];
        }
        __syncthreads();
        short8 af[4], bfr[4];
        #pragma unroll
        for (int mt=0;mt<4;mt++) af[mt]  = *(const short8*)&lA[(mh + mt*16 + r16)*32 + q*8];
        #pragma unroll
        for (int nt=0;nt<4;nt++) bfr[nt] = *(const short8*)&lB[(nh + nt*16 + r16)*32 + q*8];
        #pragma unroll
        for (int mt=0;mt<4;mt++)
            #pragma unroll
            for (int nt=0;nt<4;nt++)
                acc[mt][nt] = mfma16(af[mt], bfr[nt], acc[mt][nt]);
    }
    #pragma unroll
    for (int mt=0;mt<4;mt++){
        const int cb = mh + mt*16 + q*4;
        const float b0=bias[cb], b1=bias[cb+1], b2=bias[cb+2], b3=bias[cb+3];
        #pragma unroll
        for (int nt=0;nt<4;nt++){
            const int pos = pos0 + nh + nt*16 + r16;
            floatx4 v = acc[mt][nt];
            uint2 pk;
            pk.x = (unsigned)f2bu(v.x+b0) | ((unsigned)f2bu(v.y+b1)<<16);
            pk.y = (unsigned)f2bu(v.z+b2) | ((unsigned)f2bu(v.w+b3)<<16);
            *(uint2*)(compb + ((size_t)(b*4096)+pos)*128 + cb) = pk;
        }
    }
}

// ---- 3x3 conv as MFMA 9-shift GEMM. src NHWC bf16; cout=64 per group ----
// EPI 0: BN+SiLU -> bf16 NHWC[64] (k2).  EPI 1: fp32 NCHW (k4).
template<int CICH, int EPI>
__global__ __launch_bounds__(256) void conv3x3_mfma(
    const unsigned short* __restrict__ src, const unsigned short* __restrict__ wb,
    const float* __restrict__ p1, const float* __restrict__ p2,
    void* __restrict__ dst, int CITOT)
{
    __shared__ __align__(16) short lX[6*66*32];   // [r][c][ci] spatial-padded
    __shared__ __align__(16) short lW[9*64*32];   // [kp][cout][ci]
    const int row0 = blockIdx.x*4, b = blockIdx.y, g = blockIdx.z;
    const int tid = threadIdx.x;
    const int wave = tid>>6, lane = tid&63, q = lane>>4, r16 = lane&15;
    const int cibase = g*(CICH*32);
    const unsigned short* wsrc = wb + (size_t)g*(CICH*18432);
    floatx4 zero = {0.f,0.f,0.f,0.f};
    floatx4 acc[4][4];
    #pragma unroll
    for (int m=0;m<4;m++){ acc[m][0]=zero; acc[m][1]=zero; acc[m][2]=zero; acc[m][3]=zero; }

    for (int ch=0; ch<CICH; ch++){
        __syncthreads();
        {   // stage W chunk: contiguous 18432 shorts
            const short8* s = (const short8*)(wsrc + ch*18432);
            short8* d = (short8*)lW;
            #pragma unroll
            for (int i=0;i<9;i++) d[tid + i*256] = s[tid + i*256];
        }
        {   // stage X tile: rows row0-1..row0+4, cols -1..64, 32 ci
            const int ci = tid&31, rc0 = tid>>5;
            for (int rc=rc0; rc<396; rc+=8){
                const int r = rc/66, c = rc - r*66;
                const int gr = row0 - 1 + r, gc = c - 1;
                unsigned short v = 0;
                if ((unsigned)gr < 64u && (unsigned)gc < 64u)
                    v = src[((size_t)(b*4096) + gr*64 + gc)*CITOT + cibase + ch*32 + ci];
                lX[rc*32 + ci] = (short)v;
            }
        }
        __syncthreads();
        #pragma unroll
        for (int kp=0; kp<9; kp++){
            const int dr = kp/3, dc = kp - dr*3;
            short8 af[4], bfr[4];
            #pragma unroll
            for (int mt=0;mt<4;mt++)
                af[mt] = *(const short8*)&lW[(kp*64 + mt*16 + r16)*32 + q*8];
            #pragma unroll
            for (int nt=0;nt<4;nt++)
                bfr[nt] = *(const short8*)&lX[((wave+dr)*66 + nt*16 + r16 + dc)*32 + q*8];
            #pragma unroll
            for (int mt=0;mt<4;mt++)
                #pragma unroll
                for (int nt=0;nt<4;nt++)
                    acc[mt][nt] = mfma16(af[mt], bfr[nt], acc[mt][nt]);
        }
    }
    const int orow = row0 + wave;
    if (EPI==0){
        unsigned short* tb = (unsigned short*)dst;
        #pragma unroll
        for (int mt=0;mt<4;mt++){
            const int cb = mt*16 + q*4;
            const float a0=p1[cb],a1=p1[cb+1],a2=p1[cb+2],a3=p1[cb+3];
            const float e0=p2[cb],e1=p2[cb+1],e2=p2[cb+2],e3=p2[cb+3];
            #pragma unroll
            for (int nt=0;nt<4;nt++){
                const int pos = orow*64 + nt*16 + r16;
                floatx4 v = acc[mt][nt];
                float z0=v.x*a0+e0, z1=v.y*a1+e1, z2=v.z*a2+e2, z3=v.w*a3+e3;
                z0 = z0/(1.f+expf(-z0)); z1 = z1/(1.f+expf(-z1));
                z2 = z2/(1.f+expf(-z2)); z3 = z3/(1.f+expf(-z3));
                uint2 pk;
                pk.x = (unsigned)f2bu(z0) | ((unsigned)f2bu(z1)<<16);
                pk.y = (unsigned)f2bu(z2) | ((unsigned)f2bu(z3)<<16);
                *(uint2*)(tb + ((size_t)(b*4096)+pos)*64 + cb) = pk;
            }
        }
    } else {
        float* enh = (float*)dst;
        #pragma unroll
        for (int mt=0;mt<4;mt++){
            #pragma unroll
            for (int nt=0;nt<4;nt++){
                const int pos = orow*64 + nt*16 + r16;
                floatx4 v = acc[mt][nt];
                float* op = enh + ((size_t)(b*256) + g*64 + mt*16 + q*4)*4096 + pos;
                op[0]=v.x; op[4096]=v.y; op[8192]=v.z; op[12288]=v.w;
            }
        }
    }
}

// ---- k3: 1x1 conv t(64)->36 + softmax over groups of 9 (NHWC bf16 input) ----
__global__ __launch_bounds__(256) void k3_kpred(
    const unsigned short* __restrict__ tb, const float* __restrict__ W,
    const float* __restrict__ bias, float* __restrict__ kw)
{
    __shared__ float wl[2304];
    __shared__ float bl[36];
    for (int i=threadIdx.x;i<2304;i+=256) wl[i]=W[i];
    if (threadIdx.x<36) bl[threadIdx.x]=bias[threadIdx.x];
    __syncthreads();
    const int gid = blockIdx.x*256 + threadIdx.x;    // b*4096+pos
    const unsigned short* tp = tb + (size_t)gid*64;
    float acc[36];
    #pragma unroll
    for (int o=0;o<36;o++) acc[o]=bl[o];
    #pragma unroll
    for (int c8=0;c8<8;c8++){
        uint4 pk = *(const uint4*)(tp + c8*8);
        unsigned u[4] = {pk.x, pk.y, pk.z, pk.w};
        float f[8];
        #pragma unroll
        for (int j=0;j<4;j++){
            f[2*j]   = bu2f((unsigned short)(u[j]&0xFFFFu));
            f[2*j+1] = bu2f((unsigned short)(u[j]>>16));
        }
        #pragma unroll
        for (int jj=0;jj<8;jj++){
            const int ci = c8*8+jj;
            #pragma unroll
            for (int o=0;o<36;o++) acc[o] += f[jj]*wl[o*64+ci];
        }
    }
    float* op = kw + (size_t)gid*36;
    #pragma unroll
    for (int s=0;s<4;s++){
        float mx = acc[s*9];
        #pragma unroll
        for (int k=1;k<9;k++) mx = fmaxf(mx, acc[s*9+k]);
        float e[9]; float sum=0.f;
        #pragma unroll
        for (int k=0;k<9;k++){ e[k]=expf(acc[s*9+k]-mx); sum+=e[k]; }
        float inv = 1.f/sum;
        #pragma unroll
        for (int k=0;k<9;k++) op[s*9+k] = e[k]*inv;
    }
}

// ---- k5: reassembly + bilinear upsample add -> out (fp32) ----
template<typename T>
__device__ __forceinline__ void k5_body(
    const T* __restrict__ x, const float* __restrict__ kw,
    const float* __restrict__ enh, float* __restrict__ out)
{
    const int hi = blockIdx.x & 63;
    const int b  = blockIdx.x >> 6;
    const int c0 = blockIdx.y * 64;
    __shared__ float kwl[64*37];
    for (int i=threadIdx.x;i<2304;i+=256){
        int wi = i/36, r = i - wi*36;
        kwl[wi*37+r] = kw[((size_t)(b*4096 + hi*64 + wi))*36 + r];
    }
    __syncthreads();
    const int wi = threadIdx.x & 63;
    const int cl = threadIdx.x >> 6;
    float kreg[36];
    #pragma unroll
    for (int r=0;r<36;r++) kreg[r] = kwl[wi*37+r];

    const bool vx0 = wi>0, vx2 = wi<63;
    const bool vy0 = hi>0, vy2 = hi<63;
    const int rm = vy0? hi-1 : 0;
    const int rp = vy2? hi+1 : 63;
    const int par = wi&1;
    const int mA = wi>>1, mB = 32+mA;
    float wc0, wc1; int a0,a1,b0c,b1c;
    if (par==0){ wc0=0.25f; wc1=0.75f; a0=(mA>0)?mA-1:0; a1=mA;   b0c=mB-1; b1c=mB; }
    else       { wc0=0.75f; wc1=0.25f; a0=mA;            a1=mA+1; b0c=mB;   b1c=(mB<63)?mB+1:63; }
    const int y0 = hi*2;

    for (int c = c0+cl; c < c0+64; c += 4){
        const T* xc = x + ((size_t)(b*256)+c)*4096;
        float v[9];
        v[0] = (vy0&&vx0)? cvt(xc[(hi-1)*64+wi-1]) : 0.f;
        v[1] = (vy0)     ? cvt(xc[(hi-1)*64+wi  ]) : 0.f;
        v[2] = (vy0&&vx2)? cvt(xc[(hi-1)*64+wi+1]) : 0.f;
        v[3] = (vx0)     ? cvt(xc[ hi   *64+wi-1]) : 0.f;
        v[4] =             cvt(xc[ hi   *64+wi  ]);
        v[5] = (vx2)     ? cvt(xc[ hi   *64+wi+1]) : 0.f;
        v[6] = (vy2&&vx0)? cvt(xc[(hi+1)*64+wi-1]) : 0.f;
        v[7] = (vy2)     ? cvt(xc[(hi+1)*64+wi  ]) : 0.f;
        v[8] = (vy2&&vx2)? cvt(xc[(hi+1)*64+wi+1]) : 0.f;
        float ko[4];
        #pragma unroll
        for (int s=0;s<4;s++){
            float a = 0.f;
            #pragma unroll
            for (int k=0;k<9;k++) a += v[k]*kreg[s*9+k];
            ko[s]=a;
        }
        const float* ec = enh + ((size_t)(b*256)+c)*4096;
        const float* er0 = ec + rm*64;
        const float* er1 = ec + hi*64;
        const float* er2 = ec + rp*64;
        float uA0 = wc0*er0[a0]+wc1*er0[a1];
        float uB0 = wc0*er0[b0c]+wc1*er0[b1c];
        float uA1 = wc0*er1[a0]+wc1*er1[a1];
        float uB1 = wc0*er1[b0c]+wc1*er1[b1c];
        float uA2 = wc0*er2[a0]+wc1*er2[a1];
        float uB2 = wc0*er2[b0c]+wc1*er2[b1c];
        float up00 = 0.25f*uA0 + 0.75f*uA1;
        float up01 = 0.25f*uB0 + 0.75f*uB1;
        float up10 = 0.75f*uA1 + 0.25f*uA2;
        float up11 = 0.75f*uB1 + 0.25f*uB2;
        float* o = out + (((size_t)(b*256)+c)*128 + y0)*128;
        o[wi]      = ko[0]+up00;
        o[64+wi]   = ko[1]+up01;
        o[128+wi]  = ko[2]+up10;
        o[192+wi]  = ko[3]+up11;
    }
}

__global__ __launch_bounds__(256) void k5_fuse(
    const void* x, const float* kw, const float* enh, float* out, const float* flag)
{
    if (*flag > 0.5f) k5_body<float>((const float*)x, kw, enh, out);
    else              k5_body<bf16>((const bf16*)x, kw, enh, out);
}

// ---- k6: spatial mean ----
__global__ __launch_bounds__(256) void k6_pool(
    const float* __restrict__ out, float* __restrict__ pooled)
{
    const int bc = blockIdx.x;
    const float4* p = (const float4*)(out + (size_t)bc*16384);
    float s = 0.f;
    #pragma unroll
    for (int k=0;k<16;k++){
        float4 v = p[k*256+threadIdx.x];
        s += v.x+v.y+v.z+v.w;
    }
    __shared__ float red[4];
    for (int off=32;off>0;off>>=1) s += __shfl_down(s, off, 64);
    if ((threadIdx.x&63)==0) red[threadIdx.x>>6]=s;
    __syncthreads();
    if (threadIdx.x==0) pooled[bc] = (red[0]+red[1]+red[2]+red[3]) * (1.f/16384.f);
}

// ---- k7: SE gate ----
__global__ __launch_bounds__(256) void k7_gate(
    const float* __restrict__ pooled,
    const float* __restrict__ Wg1, const float* __restrict__ bg1,
    const float* __restrict__ Wg2, const float* __restrict__ bg2,
    float* __restrict__ gate)
{
    const int b = blockIdx.x;
    __shared__ float pl[256];
    __shared__ float hid[64];
    pl[threadIdx.x] = pooled[b*256+threadIdx.x];
    __syncthreads();
    if (threadIdx.x < 64){
        float a = bg1[threadIdx.x];
        const float* w = Wg1 + (size_t)threadIdx.x*256;
        for (int c=0;c<256;c++) a += w[c]*pl[c];
        hid[threadIdx.x] = a/(1.f+expf(-a));
    }
    __syncthreads();
    float a = bg2[threadIdx.x];
    const float* w = Wg2 + (size_t)threadIdx.x*64;
    for (int j=0;j<64;j++) a += w[j]*hid[j];
    gate[b*256+threadIdx.x] = 1.f/(1.f+expf(-a));
}

// ---- k8: out *= gate ----
__global__ __launch_bounds__(256) void k8_scale(
    float* __restrict__ out, const float* __restrict__ gate)
{
    const size_t gid = (size_t)blockIdx.x*256 + threadIdx.x;
    const float g = gate[gid>>12];
    float4* p = (float4*)out;
    float4 v = p[gid];
    v.x*=g; v.y*=g; v.z*=g; v.w*=g;
    p[gid] = v;
}

extern "C" void kernel_launch(void* const* d_in, const int* in_sizes, int n_in,
                              void* d_out, int out_size, void* d_ws, size_t ws_size,
                              hipStream_t stream)
{
    float* ws = (float*)d_ws;
    float* out = (float*)d_out;
    unsigned short* xbt   = (unsigned short*)(ws + O_XBT);
    unsigned short* compb = (unsigned short*)(ws + O_COMPB);
    unsigned short* tb    = (unsigned short*)(ws + O_TB);
    unsigned short* wkcb  = (unsigned short*)(ws + O_WKCB);
    unsigned short* wkp1b = (unsigned short*)(ws + O_WKP1B);
    unsigned short* wdefb = (unsigned short*)(ws + O_WDEFB);

    kdet<<<1, 256, 0, stream>>>((const unsigned*)d_in[1], ws + O_FLAG);
    k0_prep<<<1132, 256, 0, stream>>>(d_in[1],d_in[2],d_in[3],d_in[4],d_in[5],d_in[6],d_in[7],d_in[8],
                                      d_in[9],d_in[10],d_in[11],d_in[12],d_in[13],d_in[14],d_in[15], ws);
    k0b_pack<<<992, 256, 0, stream>>>(ws);
    xcvt<<<dim3(256,8), 256, 0, stream>>>(d_in[0], xbt, ws+O_FLAG);
    k1_mfma<<<dim3(32,8), 256, 0, stream>>>(xbt, wkcb, ws+O_BKC, compb);
    conv3x3_mfma<4,0><<<dim3(16,8,1), 256, 0, stream>>>(compb, wkp1b, ws+O_ALPHA, ws+O_BETA, (void*)tb, 128);
    k3_kpred<<<128, 256, 0, stream>>>(tb, ws+O_WKP2, ws+O_BKP2, ws+O_KW);
    conv3x3_mfma<2,1><<<dim3(16,8,4), 256, 0, stream>>>(xbt, wdefb, nullptr, nullptr, (void*)(ws+O_ENH), 256);
    k5_fuse<<<dim3(512,4), 256, 0, stream>>>(d_in[0], ws+O_KW, ws+O_ENH, out, ws+O_FLAG);
    k6_pool<<<2048, 256, 0, stream>>>(out, ws+O_POOL);
    k7_gate<<<8, 256, 0, stream>>>(ws+O_POOL, ws+O_WG1, ws+O_BG1, ws+O_WG2, ws+O_BG2, ws+O_GATE);
    k8_scale<<<32768, 256, 0, stream>>>(out, ws+O_GATE);
}